// Round 5
// baseline (350.351 us; speedup 1.0000x reference)
//
#include <hip/hip_runtime.h>

#define NN 50000
#define NE 800000
#define FIN 512
#define FHID 256
#define FOUT 128
#define MPAD 50048  // 391 * 128

#define CNT_BLOCKS  782
#define CAST_BLOCKS 12500   // NN*FIN/8/256
#define TW1_BLOCKS  512     // FIN*FHID/256
#define TW2_BLOCKS  128     // FHID*FOUT/256
#define ESTRIDE     200192  // CNT_BLOCKS*256; 4*ESTRIDE >= NE

#define NBKT 196            // buckets: dst>>8  (50000/256 -> 0..195)
#define NSUB 8              // per-XCD sub-buckets
#define SREG 768            // slots per (bucket,xcd): mean 512 + 11 sigma

#define PASSB_BLOCKS 196
#define GEMM1_BLOCKS 782    // 391 * 2

#define SNB 49              // ceil(NN/1024)

using bf16x8 = __attribute__((ext_vector_type(8))) short;
using f32x4  = __attribute__((ext_vector_type(4))) float;
using u16x8  = __attribute__((ext_vector_type(8))) unsigned short;
using u16x4  = __attribute__((ext_vector_type(4))) unsigned short;
using u16x2  = __attribute__((ext_vector_type(2))) unsigned short;

__device__ __forceinline__ unsigned short f2bf(float f) {
    unsigned int u = __builtin_bit_cast(unsigned int, f);
    unsigned int r = (u + 0x7FFFu + ((u >> 16) & 1u)) >> 16;   // RNE
    return (unsigned short)r;
}
__device__ __forceinline__ float bf2f(unsigned short u) {
    return __builtin_bit_cast(float, (unsigned int)u << 16);
}
__device__ __forceinline__ void gload_lds16(const void* g, void* l) {
    __builtin_amdgcn_global_load_lds(
        (const __attribute__((address_space(1))) void*)g,
        (__attribute__((address_space(3))) void*)l, 16, 0, 0);
}

// ---- fused pre-pass: (count_deg + bucket-scatter passA) || cast_x || transposes ----

__global__ __launch_bounds__(256) void fused_pre_kernel(
    const float* __restrict__ X, unsigned short* __restrict__ Xb,
    const int* __restrict__ src, const int* __restrict__ dst,
    const float* __restrict__ w,
    int* __restrict__ deg, int* __restrict__ bcnt, int2* __restrict__ barr,
    const float* __restrict__ W1, unsigned short* __restrict__ W1T,
    const float* __restrict__ W2, unsigned short* __restrict__ W2T) {
    int b = blockIdx.x, tid = threadIdx.x;
    if (b < CNT_BLOCKS) {
        int t = b * 256 + tid;
        int x = b & 7;  // ~XCD id (dispatch round-robin heuristic; perf-only)
        int   dd[4], ss[4];
        float wv[4];
        bool  vv[4];
#pragma unroll
        for (int j = 0; j < 4; ++j) {
            int e = t + j * ESTRIDE;
            vv[j] = e < NE;
            int ec = vv[j] ? e : 0;
            dd[j] = dst[ec]; ss[j] = src[ec]; wv[j] = w[ec];
        }
#pragma unroll
        for (int j = 0; j < 4; ++j)
            if (vv[j]) atomicAdd(&deg[dd[j]], 1);
        int cc[4], sb[4];
#pragma unroll
        for (int j = 0; j < 4; ++j) {
            if (vv[j]) {
                sb[j] = (dd[j] >> 8) * NSUB + x;
                cc[j] = atomicAdd(&bcnt[sb[j]], 1);
            }
        }
#pragma unroll
        for (int j = 0; j < 4; ++j) {
            if (vv[j] && cc[j] < SREG)
                barr[(size_t)sb[j] * SREG + cc[j]] =
                    make_int2(ss[j] | ((dd[j] & 255) << 16), __float_as_int(wv[j]));
        }
    } else if (b < CNT_BLOCKS + CAST_BLOCKS) {
        int i = (b - CNT_BLOCKS) * 256 + tid;  // exact: CAST_BLOCKS*256 == NN*FIN/8
        const float4* p = (const float4*)X + (size_t)i * 2;
        float4 a = p[0], c = p[1];
        u16x8 v;
        v[0] = f2bf(a.x); v[1] = f2bf(a.y); v[2] = f2bf(a.z); v[3] = f2bf(a.w);
        v[4] = f2bf(c.x); v[5] = f2bf(c.y); v[6] = f2bf(c.z); v[7] = f2bf(c.w);
        *(u16x8*)(Xb + (size_t)i * 8) = v;
    } else if (b < CNT_BLOCKS + CAST_BLOCKS + TW1_BLOCKS) {
        int t = (b - CNT_BLOCKS - CAST_BLOCKS) * 256 + tid;
        int n = t % FHID, k = t / FHID;
        W1T[(size_t)n * FIN + k] = f2bf(W1[t]);
    } else {
        int t = (b - CNT_BLOCKS - CAST_BLOCKS - TW1_BLOCKS) * 256 + tid;
        int n = t % FOUT, k = t / FOUT;
        W2T[(size_t)n * FHID + k] = f2bf(W2[t]);
    }
}

// ---------------- decoupled 3-pass exclusive scan of deg -> off, cur ----------------

__global__ __launch_bounds__(1024) void scan1_kernel(const int* __restrict__ deg,
                                                     int* __restrict__ bsum) {
    __shared__ int wsum[16];
    int tid = threadIdx.x, lane = tid & 63, wid = tid >> 6;
    int i = blockIdx.x * 1024 + tid;
    int v = (i < NN) ? deg[i] : 0;
#pragma unroll
    for (int d = 1; d < 64; d <<= 1) v += __shfl_xor(v, d, 64);
    if (lane == 0) wsum[wid] = v;
    __syncthreads();
    if (tid == 0) {
        int s = 0;
#pragma unroll
        for (int j = 0; j < 16; ++j) s += wsum[j];
        bsum[blockIdx.x] = s;
    }
}

__global__ void scan2_kernel(const int* __restrict__ bsum, int* __restrict__ boff,
                             int* __restrict__ off) {
    int lane = threadIdx.x;  // launched with 64 threads
    int v0 = (lane < SNB) ? bsum[lane] : 0;
    int v  = v0;
#pragma unroll
    for (int d = 1; d < 64; d <<= 1) {
        int t = __shfl_up(v, d, 64);
        if (lane >= d) v += t;
    }
    if (lane < SNB) boff[lane] = v - v0;
    if (lane == SNB - 1) off[NN] = v;
}

__global__ __launch_bounds__(1024) void scan3_kernel(int* __restrict__ cur,
                                                     const int* __restrict__ boff,
                                                     int* __restrict__ off) {
    __shared__ int wsum[16];
    int tid = threadIdx.x, lane = tid & 63, wid = tid >> 6;
    int i  = blockIdx.x * 1024 + tid;
    int v0 = (i < NN) ? cur[i] : 0;
    int v  = v0;
#pragma unroll
    for (int d = 1; d < 64; d <<= 1) {
        int t = __shfl_up(v, d, 64);
        if (lane >= d) v += t;
    }
    if (lane == 63) wsum[wid] = v;
    __syncthreads();
    int wpre = 0;
#pragma unroll
    for (int j = 0; j < 16; ++j)
        if (j < wid) wpre += wsum[j];
    int excl = boff[blockIdx.x] + wpre + v - v0;
    if (i < NN) { off[i] = excl; cur[i] = excl; }
}

// ---------------- GEMM body (128x128 tile, BK=64, 4 waves, 16x16x32 bf16 MFMA) ----------

template <int K, int N>
__device__ __forceinline__ void gemm_body(const unsigned short* __restrict__ A,
                                          const unsigned short* __restrict__ BT,
                                          unsigned short* __restrict__ C,
                                          int M, int bx, int by) {
    __shared__ unsigned short As[128 * 64];
    __shared__ unsigned short Bs[128 * 64];

    const int tid  = threadIdx.x;
    const int lane = tid & 63;
    const int wid  = tid >> 6;
    const int wm   = wid >> 1;
    const int wn   = wid & 1;
    const int brow = bx * 128;
    const int bcol = by * 128;
    const int r15   = lane & 15;
    const int khalf = (lane >> 4) * 8;

    f32x4 acc[4][4] = {};

    for (int k0 = 0; k0 < K; k0 += 64) {
#pragma unroll
        for (int c = 0; c < 4; ++c) {
            int b   = wid * 4096 + c * 1024 + lane * 16;
            int row = b >> 7;
            int cby = (b & 127) ^ ((row & 7) << 4);
            const char* ga = (const char*)(A + (size_t)(brow + row) * K + k0) + cby;
            gload_lds16(ga, (char*)As + wid * 4096 + c * 1024);
            const char* gb = (const char*)(BT + (size_t)(bcol + row) * K + k0) + cby;
            gload_lds16(gb, (char*)Bs + wid * 4096 + c * 1024);
        }
        __syncthreads();

        bf16x8 af[4][2], bfr[4][2];
#pragma unroll
        for (int m = 0; m < 4; ++m) {
            int row = wm * 64 + m * 16 + r15;
            int rb  = row * 128;
            int sw  = (row & 7) << 4;
#pragma unroll
            for (int ks = 0; ks < 2; ++ks) {
                int byte = rb + (((ks * 32 + khalf) * 2) ^ sw);
                af[m][ks] = *(const bf16x8*)((const char*)As + byte);
            }
        }
#pragma unroll
        for (int n = 0; n < 4; ++n) {
            int row = wn * 64 + n * 16 + r15;
            int rb  = row * 128;
            int sw  = (row & 7) << 4;
#pragma unroll
            for (int ks = 0; ks < 2; ++ks) {
                int byte = rb + (((ks * 32 + khalf) * 2) ^ sw);
                bfr[n][ks] = *(const bf16x8*)((const char*)Bs + byte);
            }
        }
#pragma unroll
        for (int m = 0; m < 4; ++m)
#pragma unroll
            for (int n = 0; n < 4; ++n)
#pragma unroll
                for (int ks = 0; ks < 2; ++ks)
                    acc[m][n] = __builtin_amdgcn_mfma_f32_16x16x32_bf16(
                        af[m][ks], bfr[n][ks], acc[m][n], 0, 0, 0);
        __syncthreads();
    }

    const int crow0 = brow + wm * 64;
    const int ccol0 = bcol + wn * 64 + r15;
    const int rsub  = (lane >> 4) * 4;
#pragma unroll
    for (int m = 0; m < 4; ++m) {
#pragma unroll
        for (int r = 0; r < 4; ++r) {
            int grow = crow0 + m * 16 + rsub + r;
            if (grow < M) {
#pragma unroll
                for (int n = 0; n < 4; ++n)
                    C[(size_t)grow * N + ccol0 + n * 16] = f2bf(acc[m][n][r]);
            }
        }
    }
}

// ---- pass B: one block per bucket; bucket payloads -> final CSR positions ----
// All csr writes of a bucket land in a ~32KB region owned by THIS block's CU/L2.

__device__ __forceinline__ void passb_body(int b, const int2* __restrict__ barr,
                                           const int* __restrict__ bcnt,
                                           int* __restrict__ cur,
                                           int2* __restrict__ csr) {
    int tid = threadIdx.x;
    int cnt[NSUB];
#pragma unroll
    for (int x = 0; x < NSUB; ++x) cnt[x] = min(bcnt[b * NSUB + x], SREG);
    const int2* bb = barr + (size_t)b * NSUB * SREG;
#pragma unroll
    for (int base = 0; base < NSUB * SREG; base += 1024) {
        int  g[4];
        bool v[4];
        int2 pl[4];
#pragma unroll
        for (int j = 0; j < 4; ++j) {
            g[j] = base + j * 256 + tid;
            int x = g[j] / SREG;
            int c = g[j] - x * SREG;
            v[j]  = c < cnt[x];
            pl[j] = v[j] ? bb[g[j]] : make_int2(0, 0);
        }
        int p[4];
#pragma unroll
        for (int j = 0; j < 4; ++j)
            if (v[j]) p[j] = atomicAdd(&cur[(b << 8) + ((pl[j].x >> 16) & 255)], 1);
#pragma unroll
        for (int j = 0; j < 4; ++j)
            if (v[j]) csr[p[j]] = make_int2(pl[j].x & 0xFFFF, pl[j].y);
    }
}

// ---------------- fused: passB || gemm1 ----------------

__global__ __launch_bounds__(256) void fused_gemm1_passb_kernel(
    const unsigned short* __restrict__ A, const unsigned short* __restrict__ BT,
    unsigned short* __restrict__ C,
    const int2* __restrict__ barr, const int* __restrict__ bcnt,
    int* __restrict__ cur, int2* __restrict__ csr) {
    if (blockIdx.x < PASSB_BLOCKS) {
        passb_body(blockIdx.x, barr, bcnt, cur, csr);
    } else {
        int g = blockIdx.x - PASSB_BLOCKS;
        gemm_body<FIN, FHID>(A, BT, C, NN, g % 391, g / 391);
    }
}

template <int K, int N>
__global__ __launch_bounds__(256) void gemm_bf16_kernel(const unsigned short* __restrict__ A,
                                                        const unsigned short* __restrict__ BT,
                                                        unsigned short* __restrict__ C,
                                                        int M) {
    gemm_body<K, N>(A, BT, C, M, blockIdx.x, blockIdx.y);
}

// ---------------- pull-SpMM: one wave per node, 8-wide predicated edge unroll ---------

template <int F, bool RELU, bool OUTBF>
__global__ __launch_bounds__(256) void spmm_kernel(const unsigned short* __restrict__ X,
                                                   const int* __restrict__ off,
                                                   const int2* __restrict__ csr,
                                                   void* __restrict__ Yv) {
    int gw   = (int)((blockIdx.x * 256 + threadIdx.x) >> 6);
    int lane = threadIdx.x & 63;
    if (gw >= NN) return;
    int e0 = off[gw];
    int e1 = off[gw + 1];

    if constexpr (F == 256) {
        float acc0 = 0.f, acc1 = 0.f, acc2 = 0.f, acc3 = 0.f;
        const size_t lo = (size_t)lane * 4;
        for (int e = e0; e < e1; e += 8) {
            int   ss[8];
            float ww[8];
#pragma unroll
            for (int j = 0; j < 8; ++j) {
                int  ee = e + j;
                bool v  = ee < e1;
                int2 sw = csr[v ? ee : e0];
                ss[j] = sw.x;
                ww[j] = v ? __int_as_float(sw.y) : 0.f;
            }
            u16x4 r[8];
#pragma unroll
            for (int j = 0; j < 8; ++j)
                r[j] = *(const u16x4*)(X + (size_t)ss[j] * F + lo);
#pragma unroll
            for (int j = 0; j < 8; ++j) {
                acc0 += ww[j] * bf2f(r[j][0]);
                acc1 += ww[j] * bf2f(r[j][1]);
                acc2 += ww[j] * bf2f(r[j][2]);
                acc3 += ww[j] * bf2f(r[j][3]);
            }
        }
        if (RELU) {
            acc0 = fmaxf(acc0, 0.f); acc1 = fmaxf(acc1, 0.f);
            acc2 = fmaxf(acc2, 0.f); acc3 = fmaxf(acc3, 0.f);
        }
        u16x4 o;
        o[0] = f2bf(acc0); o[1] = f2bf(acc1); o[2] = f2bf(acc2); o[3] = f2bf(acc3);
        *(u16x4*)((unsigned short*)Yv + (size_t)gw * F + lo) = o;
    } else {  // F == 128
        float acc0 = 0.f, acc1 = 0.f;
        const size_t lo = (size_t)lane * 2;
        for (int e = e0; e < e1; e += 8) {
            int   ss[8];
            float ww[8];
#pragma unroll
            for (int j = 0; j < 8; ++j) {
                int  ee = e + j;
                bool v  = ee < e1;
                int2 sw = csr[v ? ee : e0];
                ss[j] = sw.x;
                ww[j] = v ? __int_as_float(sw.y) : 0.f;
            }
            u16x2 r[8];
#pragma unroll
            for (int j = 0; j < 8; ++j)
                r[j] = *(const u16x2*)(X + (size_t)ss[j] * F + lo);
#pragma unroll
            for (int j = 0; j < 8; ++j) {
                acc0 += ww[j] * bf2f(r[j][0]);
                acc1 += ww[j] * bf2f(r[j][1]);
            }
        }
        if (RELU) { acc0 = fmaxf(acc0, 0.f); acc1 = fmaxf(acc1, 0.f); }
        float2 o = make_float2(acc0, acc1);
        *(float2*)((float*)Yv + (size_t)gw * F + lo) = o;
    }
}

// ---------------- launch ----------------

extern "C" void kernel_launch(void* const* d_in, const int* in_sizes, int n_in,
                              void* d_out, int out_size, void* d_ws, size_t ws_size,
                              hipStream_t stream) {
    const float* features = (const float*)d_in[0];
    const int*   edge_src = (const int*)d_in[1];
    const int*   edge_dst = (const int*)d_in[2];
    const float* edge_w   = (const float*)d_in[3];
    const float* W1       = (const float*)d_in[4];
    const float* W2       = (const float*)d_in[5];
    float* out = (float*)d_out;

    char*  ws  = (char*)d_ws;
    size_t ofs = 0;
    auto carve = [&](size_t bytes) -> void* {
        void* r = ws + ofs;
        ofs = (ofs + bytes + 255) & ~(size_t)255;
        return r;
    };
    int*            off   = (int*)carve((NN + 1) * sizeof(int));
    int*            cur   = (int*)carve(NN * sizeof(int));
    int*            bcnt  = (int*)carve(NBKT * NSUB * sizeof(int));
    int*            bsum  = (int*)carve(SNB * sizeof(int));
    int*            boff  = (int*)carve((SNB + 1) * sizeof(int));
    int2*           barr  = (int2*)carve((size_t)NBKT * NSUB * SREG * sizeof(int2));
    int2*           csr   = (int2*)carve((size_t)NE * sizeof(int2));
    unsigned short* Xb    = (unsigned short*)carve((size_t)MPAD * FIN * 2);
    unsigned short* W1T   = (unsigned short*)carve((size_t)FHID * FIN * 2);
    unsigned short* W2T   = (unsigned short*)carve((size_t)FOUT * FHID * 2);
    unsigned short* H0b   = (unsigned short*)carve((size_t)MPAD * FHID * 2);
    unsigned short* Hb    = (unsigned short*)carve((size_t)MPAD * FHID * 2);
    unsigned short* H1b   = H0b;  // H0b dead after spmm1

    // zero cur (deg) + bcnt in one span (they are carved adjacently)
    size_t zspan = (size_t)((char*)bcnt + NBKT * NSUB * sizeof(int) - (char*)cur);
    hipMemsetAsync(cur, 0, zspan, stream);

    // (count_deg + bucket passA) || cast_x || transpose W1 || transpose W2
    fused_pre_kernel<<<CNT_BLOCKS + CAST_BLOCKS + TW1_BLOCKS + TW2_BLOCKS, 256, 0, stream>>>(
        features, Xb, edge_src, edge_dst, edge_w, cur, bcnt, barr, W1, W1T, W2, W2T);

    // decoupled scan: deg -> off (and cursor copy in cur)
    scan1_kernel<<<SNB, 1024, 0, stream>>>(cur, bsum);
    scan2_kernel<<<1, 64, 0, stream>>>(bsum, boff, off);
    scan3_kernel<<<SNB, 1024, 0, stream>>>(cur, boff, off);

    // passB (CSR finalize) || gemm1 (H0 = X @ W1)
    fused_gemm1_passb_kernel<<<PASSB_BLOCKS + GEMM1_BLOCKS, 256, 0, stream>>>(
        Xb, W1T, H0b, barr, bcnt, cur, csr);

    // hidden = relu(A @ H0)  (bf16)
    spmm_kernel<FHID, true, true><<<12500, 256, 0, stream>>>(H0b, off, csr, Hb);

    // H1 = hidden @ W2 ; out = A @ H1
    gemm_bf16_kernel<FHID, FOUT><<<dim3(391, 1), 256, 0, stream>>>(Hb, W2T, H1b, NN);
    spmm_kernel<FOUT, false, false><<<12500, 256, 0, stream>>>(H1b, off, csr, out);
}

// Round 6
// 254.386 us; speedup vs baseline: 1.3772x; 1.3772x over previous
//
#include <hip/hip_runtime.h>

#define NN 50000
#define NE 800000
#define FIN 512
#define FHID 256
#define FOUT 128
#define MPAD 50048  // 391 * 128

#define CNT_BLOCKS  782
#define CAST_BLOCKS 12500   // NN*FIN/8/256
#define TW1_BLOCKS  512     // FIN*FHID/256
#define TW2_BLOCKS  128     // FHID*FOUT/256
#define ESTRIDE     200192  // CNT_BLOCKS*256; 4*ESTRIDE >= NE

// XCD-partitioned scatter: 98 groups x 8 partition-blocks; each group scans
// an 8192-edge chunk, each block keeps only dst in its 1/8 of node space.
#define SCAT_GROUPS 98
#define SCAT_BLOCKS 784     // 8 * SCAT_GROUPS
#define E_CH        8192    // 98 * 8192 = 802816 >= NE
#define PBOUND      6250    // NN / 8

#define GEMM1_BLOCKS 782    // 391 * 2

#define SNB 49              // ceil(NN/1024)

using bf16x8 = __attribute__((ext_vector_type(8))) short;
using f32x4  = __attribute__((ext_vector_type(4))) float;
using u16x8  = __attribute__((ext_vector_type(8))) unsigned short;
using u16x4  = __attribute__((ext_vector_type(4))) unsigned short;
using u16x2  = __attribute__((ext_vector_type(2))) unsigned short;

__device__ __forceinline__ unsigned short f2bf(float f) {
    unsigned int u = __builtin_bit_cast(unsigned int, f);
    unsigned int r = (u + 0x7FFFu + ((u >> 16) & 1u)) >> 16;   // RNE
    return (unsigned short)r;
}
__device__ __forceinline__ float bf2f(unsigned short u) {
    return __builtin_bit_cast(float, (unsigned int)u << 16);
}
__device__ __forceinline__ void gload_lds16(const void* g, void* l) {
    __builtin_amdgcn_global_load_lds(
        (const __attribute__((address_space(1))) void*)g,
        (__attribute__((address_space(3))) void*)l, 16, 0, 0);
}

// ---- fused pre-pass: count_deg || cast_x || transpose W1 || transpose W2 ----

__global__ __launch_bounds__(256) void fused_pre_kernel(
    const float* __restrict__ X, unsigned short* __restrict__ Xb,
    const int* __restrict__ dst, int* __restrict__ deg,
    const float* __restrict__ W1, unsigned short* __restrict__ W1T,
    const float* __restrict__ W2, unsigned short* __restrict__ W2T) {
    int b = blockIdx.x, tid = threadIdx.x;
    if (b < CNT_BLOCKS) {
        int t  = b * 256 + tid;
        int e3 = t + 3 * ESTRIDE;
        bool v3 = e3 < NE;   // e0..e2 always < NE
        int d0 = dst[t];
        int d1 = dst[t + ESTRIDE];
        int d2 = dst[t + 2 * ESTRIDE];
        int d3 = v3 ? dst[e3] : 0;
        atomicAdd(&deg[d0], 1);
        atomicAdd(&deg[d1], 1);
        atomicAdd(&deg[d2], 1);
        if (v3) atomicAdd(&deg[d3], 1);
    } else if (b < CNT_BLOCKS + CAST_BLOCKS) {
        int i = (b - CNT_BLOCKS) * 256 + tid;  // exact: CAST_BLOCKS*256 == NN*FIN/8
        const float4* p = (const float4*)X + (size_t)i * 2;
        float4 a = p[0], c = p[1];
        u16x8 v;
        v[0] = f2bf(a.x); v[1] = f2bf(a.y); v[2] = f2bf(a.z); v[3] = f2bf(a.w);
        v[4] = f2bf(c.x); v[5] = f2bf(c.y); v[6] = f2bf(c.z); v[7] = f2bf(c.w);
        *(u16x8*)(Xb + (size_t)i * 8) = v;
    } else if (b < CNT_BLOCKS + CAST_BLOCKS + TW1_BLOCKS) {
        int t = (b - CNT_BLOCKS - CAST_BLOCKS) * 256 + tid;
        int n = t % FHID, k = t / FHID;
        W1T[(size_t)n * FIN + k] = f2bf(W1[t]);
    } else {
        int t = (b - CNT_BLOCKS - CAST_BLOCKS - TW1_BLOCKS) * 256 + tid;
        int n = t % FOUT, k = t / FOUT;
        W2T[(size_t)n * FHID + k] = f2bf(W2[t]);
    }
}

// ---------------- decoupled 3-pass exclusive scan of deg -> off, cur ----------------

__global__ __launch_bounds__(1024) void scan1_kernel(const int* __restrict__ deg,
                                                     int* __restrict__ bsum) {
    __shared__ int wsum[16];
    int tid = threadIdx.x, lane = tid & 63, wid = tid >> 6;
    int i = blockIdx.x * 1024 + tid;
    int v = (i < NN) ? deg[i] : 0;
#pragma unroll
    for (int d = 1; d < 64; d <<= 1) v += __shfl_xor(v, d, 64);
    if (lane == 0) wsum[wid] = v;
    __syncthreads();
    if (tid == 0) {
        int s = 0;
#pragma unroll
        for (int j = 0; j < 16; ++j) s += wsum[j];
        bsum[blockIdx.x] = s;
    }
}

__global__ void scan2_kernel(const int* __restrict__ bsum, int* __restrict__ boff,
                             int* __restrict__ off) {
    int lane = threadIdx.x;  // launched with 64 threads
    int v0 = (lane < SNB) ? bsum[lane] : 0;
    int v  = v0;
#pragma unroll
    for (int d = 1; d < 64; d <<= 1) {
        int t = __shfl_up(v, d, 64);
        if (lane >= d) v += t;
    }
    if (lane < SNB) boff[lane] = v - v0;
    if (lane == SNB - 1) off[NN] = v;
}

__global__ __launch_bounds__(1024) void scan3_kernel(int* __restrict__ cur,
                                                     const int* __restrict__ boff,
                                                     int* __restrict__ off) {
    __shared__ int wsum[16];
    int tid = threadIdx.x, lane = tid & 63, wid = tid >> 6;
    int i  = blockIdx.x * 1024 + tid;
    int v0 = (i < NN) ? cur[i] : 0;
    int v  = v0;
#pragma unroll
    for (int d = 1; d < 64; d <<= 1) {
        int t = __shfl_up(v, d, 64);
        if (lane >= d) v += t;
    }
    if (lane == 63) wsum[wid] = v;
    __syncthreads();
    int wpre = 0;
#pragma unroll
    for (int j = 0; j < 16; ++j)
        if (j < wid) wpre += wsum[j];
    int excl = boff[blockIdx.x] + wpre + v - v0;
    if (i < NN) { off[i] = excl; cur[i] = excl; }
}

// ---------------- GEMM body (128x128 tile, BK=64, 4 waves, 16x16x32 bf16 MFMA) ----------

template <int K, int N>
__device__ __forceinline__ void gemm_body(const unsigned short* __restrict__ A,
                                          const unsigned short* __restrict__ BT,
                                          unsigned short* __restrict__ C,
                                          int M, int bx, int by) {
    __shared__ unsigned short As[128 * 64];
    __shared__ unsigned short Bs[128 * 64];

    const int tid  = threadIdx.x;
    const int lane = tid & 63;
    const int wid  = tid >> 6;
    const int wm   = wid >> 1;
    const int wn   = wid & 1;
    const int brow = bx * 128;
    const int bcol = by * 128;
    const int r15   = lane & 15;
    const int khalf = (lane >> 4) * 8;

    f32x4 acc[4][4] = {};

    for (int k0 = 0; k0 < K; k0 += 64) {
#pragma unroll
        for (int c = 0; c < 4; ++c) {
            int b   = wid * 4096 + c * 1024 + lane * 16;
            int row = b >> 7;
            int cby = (b & 127) ^ ((row & 7) << 4);
            const char* ga = (const char*)(A + (size_t)(brow + row) * K + k0) + cby;
            gload_lds16(ga, (char*)As + wid * 4096 + c * 1024);
            const char* gb = (const char*)(BT + (size_t)(bcol + row) * K + k0) + cby;
            gload_lds16(gb, (char*)Bs + wid * 4096 + c * 1024);
        }
        __syncthreads();

        bf16x8 af[4][2], bfr[4][2];
#pragma unroll
        for (int m = 0; m < 4; ++m) {
            int row = wm * 64 + m * 16 + r15;
            int rb  = row * 128;
            int sw  = (row & 7) << 4;
#pragma unroll
            for (int ks = 0; ks < 2; ++ks) {
                int byte = rb + (((ks * 32 + khalf) * 2) ^ sw);
                af[m][ks] = *(const bf16x8*)((const char*)As + byte);
            }
        }
#pragma unroll
        for (int n = 0; n < 4; ++n) {
            int row = wn * 64 + n * 16 + r15;
            int rb  = row * 128;
            int sw  = (row & 7) << 4;
#pragma unroll
            for (int ks = 0; ks < 2; ++ks) {
                int byte = rb + (((ks * 32 + khalf) * 2) ^ sw);
                bfr[n][ks] = *(const bf16x8*)((const char*)Bs + byte);
            }
        }
#pragma unroll
        for (int m = 0; m < 4; ++m)
#pragma unroll
            for (int n = 0; n < 4; ++n)
#pragma unroll
                for (int ks = 0; ks < 2; ++ks)
                    acc[m][n] = __builtin_amdgcn_mfma_f32_16x16x32_bf16(
                        af[m][ks], bfr[n][ks], acc[m][n], 0, 0, 0);
        __syncthreads();
    }

    const int crow0 = brow + wm * 64;
    const int ccol0 = bcol + wn * 64 + r15;
    const int rsub  = (lane >> 4) * 4;
#pragma unroll
    for (int m = 0; m < 4; ++m) {
#pragma unroll
        for (int r = 0; r < 4; ++r) {
            int grow = crow0 + m * 16 + rsub + r;
            if (grow < M) {
#pragma unroll
                for (int n = 0; n < 4; ++n)
                    C[(size_t)grow * N + ccol0 + n * 16] = f2bf(acc[m][n][r]);
            }
        }
    }
}

// ---- scatter body: XCD-partitioned. Block (gid,part) scans chunk gid and keeps
// edges with dst in partition `part` -> csr lines + cursors owned by ONE XCD ----

__device__ __forceinline__ void scatter_body(int sbid,
                                             const int* __restrict__ src,
                                             const int* __restrict__ dst,
                                             const float* __restrict__ w,
                                             int* __restrict__ cur,
                                             int2* __restrict__ csr) {
    int gid  = sbid >> 3;
    int part = sbid & 7;          // == XCD id under round-robin dispatch (perf heuristic)
    int lo   = part * PBOUND, hi = lo + PBOUND;
    int base = gid * E_CH + threadIdx.x;
#pragma unroll
    for (int it = 0; it < 4; ++it) {
        int  e[8], d[8];
        bool m[8];
#pragma unroll
        for (int j = 0; j < 8; ++j) {
            e[j] = base + (it * 8 + j) * 256;
            bool inb = e[j] < NE;
            d[j] = inb ? dst[e[j]] : 0;
            m[j] = inb && d[j] >= lo && d[j] < hi;
        }
        int   s[8];
        float wv[8];
#pragma unroll
        for (int j = 0; j < 8; ++j) {
            s[j]  = m[j] ? src[e[j]] : 0;
            wv[j] = m[j] ? w[e[j]] : 0.f;
        }
        int p[8];
#pragma unroll
        for (int j = 0; j < 8; ++j)
            if (m[j]) p[j] = atomicAdd(&cur[d[j]], 1);
#pragma unroll
        for (int j = 0; j < 8; ++j)
            if (m[j]) csr[p[j]] = make_int2(s[j], __float_as_int(wv[j]));
    }
}

// ---------------- fused: scatter (first, for blockIdx%8 -> XCD) || gemm1 ----------------

__global__ __launch_bounds__(256) void fused_gemm1_scatter_kernel(
    const unsigned short* __restrict__ A, const unsigned short* __restrict__ BT,
    unsigned short* __restrict__ C,
    const int* __restrict__ src, const int* __restrict__ dst,
    const float* __restrict__ w, int* __restrict__ cur, int2* __restrict__ csr) {
    if (blockIdx.x < SCAT_BLOCKS) {
        scatter_body(blockIdx.x, src, dst, w, cur, csr);
    } else {
        int g = blockIdx.x - SCAT_BLOCKS;
        gemm_body<FIN, FHID>(A, BT, C, NN, g % 391, g / 391);
    }
}

template <int K, int N>
__global__ __launch_bounds__(256) void gemm_bf16_kernel(const unsigned short* __restrict__ A,
                                                        const unsigned short* __restrict__ BT,
                                                        unsigned short* __restrict__ C,
                                                        int M) {
    gemm_body<K, N>(A, BT, C, M, blockIdx.x, blockIdx.y);
}

// ---------------- pull-SpMM: one wave per node, 8-wide predicated edge unroll ---------

template <int F, bool RELU, bool OUTBF>
__global__ __launch_bounds__(256) void spmm_kernel(const unsigned short* __restrict__ X,
                                                   const int* __restrict__ off,
                                                   const int2* __restrict__ csr,
                                                   void* __restrict__ Yv) {
    int gw   = (int)((blockIdx.x * 256 + threadIdx.x) >> 6);
    int lane = threadIdx.x & 63;
    if (gw >= NN) return;
    int e0 = off[gw];
    int e1 = off[gw + 1];

    if constexpr (F == 256) {
        float acc0 = 0.f, acc1 = 0.f, acc2 = 0.f, acc3 = 0.f;
        const size_t lo = (size_t)lane * 4;
        for (int e = e0; e < e1; e += 8) {
            int   ss[8];
            float ww[8];
#pragma unroll
            for (int j = 0; j < 8; ++j) {
                int  ee = e + j;
                bool v  = ee < e1;
                int2 sw = csr[v ? ee : e0];
                ss[j] = sw.x;
                ww[j] = v ? __int_as_float(sw.y) : 0.f;
            }
            u16x4 r[8];
#pragma unroll
            for (int j = 0; j < 8; ++j)
                r[j] = *(const u16x4*)(X + (size_t)ss[j] * F + lo);
#pragma unroll
            for (int j = 0; j < 8; ++j) {
                acc0 += ww[j] * bf2f(r[j][0]);
                acc1 += ww[j] * bf2f(r[j][1]);
                acc2 += ww[j] * bf2f(r[j][2]);
                acc3 += ww[j] * bf2f(r[j][3]);
            }
        }
        if (RELU) {
            acc0 = fmaxf(acc0, 0.f); acc1 = fmaxf(acc1, 0.f);
            acc2 = fmaxf(acc2, 0.f); acc3 = fmaxf(acc3, 0.f);
        }
        u16x4 o;
        o[0] = f2bf(acc0); o[1] = f2bf(acc1); o[2] = f2bf(acc2); o[3] = f2bf(acc3);
        *(u16x4*)((unsigned short*)Yv + (size_t)gw * F + lo) = o;
    } else {  // F == 128
        float acc0 = 0.f, acc1 = 0.f;
        const size_t lo = (size_t)lane * 2;
        for (int e = e0; e < e1; e += 8) {
            int   ss[8];
            float ww[8];
#pragma unroll
            for (int j = 0; j < 8; ++j) {
                int  ee = e + j;
                bool v  = ee < e1;
                int2 sw = csr[v ? ee : e0];
                ss[j] = sw.x;
                ww[j] = v ? __int_as_float(sw.y) : 0.f;
            }
            u16x2 r[8];
#pragma unroll
            for (int j = 0; j < 8; ++j)
                r[j] = *(const u16x2*)(X + (size_t)ss[j] * F + lo);
#pragma unroll
            for (int j = 0; j < 8; ++j) {
                acc0 += ww[j] * bf2f(r[j][0]);
                acc1 += ww[j] * bf2f(r[j][1]);
            }
        }
        if (RELU) { acc0 = fmaxf(acc0, 0.f); acc1 = fmaxf(acc1, 0.f); }
        float2 o = make_float2(acc0, acc1);
        *(float2*)((float*)Yv + (size_t)gw * F + lo) = o;
    }
}

// ---------------- launch ----------------

extern "C" void kernel_launch(void* const* d_in, const int* in_sizes, int n_in,
                              void* d_out, int out_size, void* d_ws, size_t ws_size,
                              hipStream_t stream) {
    const float* features = (const float*)d_in[0];
    const int*   edge_src = (const int*)d_in[1];
    const int*   edge_dst = (const int*)d_in[2];
    const float* edge_w   = (const float*)d_in[3];
    const float* W1       = (const float*)d_in[4];
    const float* W2       = (const float*)d_in[5];
    float* out = (float*)d_out;

    char*  ws  = (char*)d_ws;
    size_t ofs = 0;
    auto carve = [&](size_t bytes) -> void* {
        void* r = ws + ofs;
        ofs = (ofs + bytes + 255) & ~(size_t)255;
        return r;
    };
    int*            off   = (int*)carve((NN + 1) * sizeof(int));
    int*            cur   = (int*)carve(NN * sizeof(int));
    int*            bsum  = (int*)carve(SNB * sizeof(int));
    int*            boff  = (int*)carve((SNB + 1) * sizeof(int));
    int2*           csr   = (int2*)carve((size_t)NE * sizeof(int2));
    unsigned short* Xb    = (unsigned short*)carve((size_t)MPAD * FIN * 2);
    unsigned short* W1T   = (unsigned short*)carve((size_t)FHID * FIN * 2);
    unsigned short* W2T   = (unsigned short*)carve((size_t)FOUT * FHID * 2);
    unsigned short* H0b   = (unsigned short*)carve((size_t)MPAD * FHID * 2);
    unsigned short* Hb    = (unsigned short*)carve((size_t)MPAD * FHID * 2);
    unsigned short* H1b   = H0b;  // H0b dead after spmm1

    hipMemsetAsync(cur, 0, NN * sizeof(int), stream);

    // count_deg || cast_x || transpose W1 || transpose W2
    fused_pre_kernel<<<CNT_BLOCKS + CAST_BLOCKS + TW1_BLOCKS + TW2_BLOCKS, 256, 0, stream>>>(
        features, Xb, edge_dst, cur, W1, W1T, W2, W2T);

    // decoupled scan: deg -> off (and cursor copy in cur)
    scan1_kernel<<<SNB, 1024, 0, stream>>>(cur, bsum);
    scan2_kernel<<<1, 64, 0, stream>>>(bsum, boff, off);
    scan3_kernel<<<SNB, 1024, 0, stream>>>(cur, boff, off);

    // scatter (XCD-partitioned CSR fill) || gemm1 (H0 = X @ W1)
    fused_gemm1_scatter_kernel<<<SCAT_BLOCKS + GEMM1_BLOCKS, 256, 0, stream>>>(
        Xb, W1T, H0b, edge_src, edge_dst, edge_w, cur, csr);

    // hidden = relu(A @ H0)  (bf16)
    spmm_kernel<FHID, true, true><<<12500, 256, 0, stream>>>(H0b, off, csr, Hb);

    // H1 = hidden @ W2 ; out = A @ H1
    gemm_bf16_kernel<FHID, FOUT><<<dim3(391, 1), 256, 0, stream>>>(Hb, W2T, H1b, NN);
    spmm_kernel<FOUT, false, false><<<12500, 256, 0, stream>>>(H1b, off, csr, out);
}